// Round 6
// baseline (489.090 us; speedup 1.0000x reference)
//
#include <hip/hip_runtime.h>
#include <hip/hip_bf16.h>
#include <math.h>

typedef __attribute__((ext_vector_type(8))) short short8;
typedef __attribute__((ext_vector_type(4))) float floatx4;

__device__ __forceinline__ short f2bits(float f) {
    union { float f; unsigned u; } cv; cv.f = f;
    unsigned u = cv.u;
    u += 0x7fffu + ((u >> 16) & 1u);   // RNE fp32 -> bf16
    return (short)(u >> 16);
}

__device__ __forceinline__ floatx4 mfma16(short8 a, short8 b, floatx4 c) {
    return __builtin_amdgcn_mfma_f32_16x16x32_bf16(a, b, c, 0, 0, 0);
}

typedef const __attribute__((address_space(1))) unsigned int* gas_ptr;
typedef __attribute__((address_space(3))) unsigned int* las_ptr;

// async 16B global->LDS: lands at (wave-uniform base + lane*16)
__device__ __forceinline__ void gl2lds16(const short* g, short* l) {
    __builtin_amdgcn_global_load_lds((gas_ptr)g, (las_ptr)l, 16, 0, 0);
}

// ================= k_front: fused msum / dmean / tr / pe / prep =================
// [0,1024): msum   [1024,1152): dmean   [1152,3456): transpose
// [3456,3472): pe_proj   [3472,5520): A1 build
__global__ __launch_bounds__(256) void k_front(
    const float* __restrict__ w_delta, const float* __restrict__ w_xproj,
    const float* __restrict__ w_phys,  const float* __restrict__ w_outp,
    const float* __restrict__ w_gate,  const float* __restrict__ w_fuse,
    short* __restrict__ bt_delta, short* __restrict__ bt_xproj,
    short* __restrict__ bt_phys,  short* __restrict__ bt_outp,
    short* __restrict__ bt_gate,  short* __restrict__ bt_fuse,
    const float* __restrict__ x, const float* __restrict__ ms,
    const float* __restrict__ seqW, const float* __restrict__ seqb,
    short* __restrict__ A1, float* __restrict__ pe_proj,
    float* __restrict__ msum, float* __restrict__ dmean)
{
    __shared__ float sf[32 * 33];
    __shared__ float pe[512];
    __shared__ float red[512];
    int bi = blockIdx.x;
    int t = threadIdx.x;
    if (bi < 1024) {
        // ---- msum: bt = bi>>4, 64-row slab; 2 halves of 32 rows ----
        int bt = bi >> 4, lc = bi & 15;
        int tn = t & 127, half = t >> 7;
        int d4 = tn << 2;
        const float* base = ms + ((size_t)(bt * 1024 + lc * 64 + half * 32)) * 512 + d4;
        float4 acc = {0, 0, 0, 0};
#pragma unroll 8
        for (int l = 0; l < 32; ++l) {
            float4 v = *(const float4*)(base + (size_t)l * 512);
            acc.x += v.x; acc.y += v.y; acc.z += v.z; acc.w += v.w;
        }
        if (half) *(float4*)(red + d4) = acc;
        __syncthreads();
        if (!half) {
            float4 o = *(const float4*)(red + d4);
            float* dst = msum + bt * 512 + d4;
            atomicAdd(dst + 0, acc.x + o.x); atomicAdd(dst + 1, acc.y + o.y);
            atomicAdd(dst + 2, acc.z + o.z); atomicAdd(dst + 3, acc.w + o.w);
        }
    } else if (bi < 1152) {
        // ---- dmean: 128 blocks = 4b x 32 slabs of 32 rows; 2 halves of 16 ----
        int local = bi - 1024;
        int b = local >> 5, lc = local & 31;
        int tn = t & 127, half = t >> 7;
        int d4 = tn << 2;
        int r0 = lc * 32 + half * 16;
        float4 acc = {0, 0, 0, 0};
#pragma unroll 8
        for (int l = 0; l < 16; ++l) {
            int lr = r0 + l;
            float4 xv = *(const float4*)(x + ((size_t)(b * 1024 + lr)) * 512 + d4);
            float4 pv = *(const float4*)(ms + ((size_t)(b * 16 + 15) * 1024 + lr) * 512 + d4);
            acc.x += xv.x - pv.x; acc.y += xv.y - pv.y;
            acc.z += xv.z - pv.z; acc.w += xv.w - pv.w;
        }
        if (half) *(float4*)(red + d4) = acc;
        __syncthreads();
        if (!half) {
            float4 o = *(const float4*)(red + d4);
            float* dst = dmean + b * 512 + d4;
            atomicAdd(dst + 0, acc.x + o.x); atomicAdd(dst + 1, acc.y + o.y);
            atomicAdd(dst + 2, acc.z + o.z); atomicAdd(dst + 3, acc.w + o.w);
        }
    } else if (bi < 3456) {
        // ---- 32x32 LDS transpose + fp32->bf16 ----
        int id = bi - 1152;
        const float* W; short* BT; int K; int local;
        if (id < 256)        { W = w_delta; BT = bt_delta; K = 512;  local = id; }
        else if (id < 512)   { W = w_xproj; BT = bt_xproj; K = 512;  local = id - 256; }
        else if (id < 768)   { W = w_phys;  BT = bt_phys;  K = 512;  local = id - 512; }
        else if (id < 1024)  { W = w_outp;  BT = bt_outp;  K = 512;  local = id - 768; }
        else if (id < 1792)  { W = w_gate;  BT = bt_gate;  K = 1536; local = id - 1024; }
        else                 { W = w_fuse;  BT = bt_fuse;  K = 1024; local = id - 1792; }
        int kt = local >> 4, nt = local & 15;
        int r = t >> 3, c = (t & 7) * 4;
        float4 v = *(const float4*)(W + (size_t)(kt * 32 + r) * 512 + nt * 32 + c);
        sf[r * 33 + c + 0] = v.x; sf[r * 33 + c + 1] = v.y;
        sf[r * 33 + c + 2] = v.z; sf[r * 33 + c + 3] = v.w;
        __syncthreads();
        int n = t >> 3, k4 = (t & 7) * 4;
        short4 o;
        o.x = f2bits(sf[(k4 + 0) * 33 + n]);
        o.y = f2bits(sf[(k4 + 1) * 33 + n]);
        o.z = f2bits(sf[(k4 + 2) * 33 + n]);
        o.w = f2bits(sf[(k4 + 3) * 33 + n]);
        *(short4*)(BT + (size_t)(nt * 32 + n) * K + kt * 32 + k4) = o;
    } else if (bi < 3472) {
        // ---- pe_proj[t][n] ----
        int tt = bi - 3456;
        for (int d = t; d < 512; d += 256) {
            int i = d >> 1;
            float div = expf(-9.210340371976184f * (2.f * i / 512.f));
            float ang = (float)(tt + 1) * div;
            pe[d] = (d & 1) ? cosf(ang) : sinf(ang);
        }
        __syncthreads();
        for (int n = t; n < 512; n += 256) {
            float acc = 0.f;
#pragma unroll 4
            for (int d = 0; d < 512; ++d) acc += pe[d] * seqW[(size_t)d * 512 + n];
            pe_proj[tt * 512 + n] = acc + seqb[n];
        }
    } else {
        // ---- A1 = [delta | x | x_phys] bf16 ----
        int gid = (bi - 3472) * 256 + t;
        int r = gid >> 7;
        int c4 = (gid & 127) << 2;
        int b = r >> 10, l = r & 1023;
        float4 xv = *(const float4*)(x + (size_t)r * 512 + c4);
        float4 pv = *(const float4*)(ms + ((size_t)(b * 16 + 15) * 1024 + l) * 512 + c4);
        short4 xb, pb, db;
        xb.x = f2bits(xv.x); xb.y = f2bits(xv.y); xb.z = f2bits(xv.z); xb.w = f2bits(xv.w);
        pb.x = f2bits(pv.x); pb.y = f2bits(pv.y); pb.z = f2bits(pv.z); pb.w = f2bits(pv.w);
        db.x = f2bits(xv.x - pv.x); db.y = f2bits(xv.y - pv.y);
        db.z = f2bits(xv.z - pv.z); db.w = f2bits(xv.w - pv.w);
        short* row = A1 + (size_t)r * 1536;
        *(short4*)(row + c4) = db;
        *(short4*)(row + 512 + c4) = xb;
        *(short4*)(row + 1024 + c4) = pb;
    }
}

// ---------------- xrm[b][d] = sum_l (x + raw_memory), 128 blocks ----------------
__global__ __launch_bounds__(256) void k_rmean(const float* __restrict__ x, const float* __restrict__ rawm,
                                               float* __restrict__ xrm)
{
    __shared__ float red[512];
    int b = blockIdx.x >> 5, lc = blockIdx.x & 31;
    int t = threadIdx.x;
    int tn = t & 127, half = t >> 7;
    int d4 = tn << 2;
    int r0 = lc * 32 + half * 16;
    float4 acc = {0, 0, 0, 0};
#pragma unroll 8
    for (int l = 0; l < 16; ++l) {
        size_t idx = ((size_t)(b * 1024 + r0 + l)) * 512 + d4;
        float4 v = *(const float4*)(x + idx);
        float4 rm = *(const float4*)(rawm + idx);
        acc.x += v.x + rm.x; acc.y += v.y + rm.y;
        acc.z += v.z + rm.z; acc.w += v.w + rm.w;
    }
    if (half) *(float4*)(red + d4) = acc;
    __syncthreads();
    if (!half) {
        float4 o = *(const float4*)(red + d4);
        float* dst = xrm + b * 512 + d4;
        atomicAdd(dst + 0, acc.x + o.x); atomicAdd(dst + 1, acc.y + o.y);
        atomicAdd(dst + 2, acc.z + o.z); atomicAdd(dst + 3, acc.w + o.w);
    }
}

// ================= fused front GEMM -> H (bf16).  BM=BN=64, BK=64 =================
__global__ __launch_bounds__(256) void gemm_h_t(
    const short* __restrict__ A1,
    const short* __restrict__ BTd, const short* __restrict__ BTx,
    const short* __restrict__ BTp, const short* __restrict__ BTg,
    const float* __restrict__ bd, const float* __restrict__ bx,
    const float* __restrict__ bp, const float* __restrict__ bg,
    short* __restrict__ H)
{
    __shared__ __align__(16) short As[4096], Bgs[4096], Bss[4096];
    int bm = blockIdx.x >> 3, bn = blockIdx.x & 7;
    int t = threadIdx.x, lane = t & 63;
    int wm = (t >> 6) & 1, wn = t >> 7;
    int l15 = lane & 15, quad = lane >> 4;
    int tr8 = t >> 3, pc = t & 7;

    int row0 = tr8, row1 = 32 + tr8;
    int lc0 = (pc - (row0 >> 1)) & 7, lc1 = (pc - (row1 >> 1)) & 7;
    const short* gaA0 = A1 + (size_t)(bm * 64 + row0) * 1536 + lc0 * 8;
    const short* gaA1 = A1 + (size_t)(bm * 64 + row1) * 1536 + lc1 * 8;
    const short* gaG0 = BTg + (size_t)(bn * 64 + row0) * 1536 + lc0 * 8;
    const short* gaG1 = BTg + (size_t)(bn * 64 + row1) * 1536 + lc1 * 8;
    const short* gd0 = BTd + (size_t)(bn * 64 + row0) * 512 + lc0 * 8;
    const short* gd1 = BTd + (size_t)(bn * 64 + row1) * 512 + lc1 * 8;
    const short* gx0 = BTx + (size_t)(bn * 64 + row0) * 512 + lc0 * 8;
    const short* gx1 = BTx + (size_t)(bn * 64 + row1) * 512 + lc1 * 8;
    const short* gp0 = BTp + (size_t)(bn * 64 + row0) * 512 + lc0 * 8;
    const short* gp1 = BTp + (size_t)(bn * 64 + row1) * 512 + lc1 * 8;
    short* ldA0 = As + t * 8;  short* ldA1 = As + 2048 + t * 8;
    short* ldG0 = Bgs + t * 8; short* ldG1 = Bgs + 2048 + t * 8;
    short* ldS0 = Bss + t * 8; short* ldS1 = Bss + 2048 + t * 8;

    const short *ra[2][2], *rg[2][2], *rs[2][2];
#pragma unroll
    for (int mi = 0; mi < 2; ++mi)
#pragma unroll
        for (int ki = 0; ki < 2; ++ki) {
            int row = wm * 32 + mi * 16 + l15;
            int off = row * 64 + ((ki * 4 + quad + (row >> 1)) & 7) * 8;
            ra[mi][ki] = As + off;
            int rowb = wn * 32 + mi * 16 + l15;
            int offb = rowb * 64 + ((ki * 4 + quad + (rowb >> 1)) & 7) * 8;
            rg[mi][ki] = Bgs + offb;
            rs[mi][ki] = Bss + offb;
        }

    floatx4 accg[2][2], accd[2][2], accx[2][2], accp[2][2];
#pragma unroll
    for (int i = 0; i < 2; ++i)
#pragma unroll
        for (int j = 0; j < 2; ++j) {
            accg[i][j] = (floatx4){0,0,0,0}; accd[i][j] = (floatx4){0,0,0,0};
            accx[i][j] = (floatx4){0,0,0,0}; accp[i][j] = (floatx4){0,0,0,0};
        }

#define HPHASE(S0, S1, ACC, KB)                                                  \
    for (int k0 = 0; k0 < 512; k0 += 64) {                                       \
        gl2lds16(gaA0 + KB + k0, ldA0); gl2lds16(gaA1 + KB + k0, ldA1);          \
        gl2lds16(gaG0 + KB + k0, ldG0); gl2lds16(gaG1 + KB + k0, ldG1);          \
        gl2lds16(S0 + k0, ldS0);        gl2lds16(S1 + k0, ldS1);                 \
        __syncthreads();                                                         \
        short8 av[2][2], gv[2][2], sv[2][2];                                     \
        _Pragma("unroll") for (int mi = 0; mi < 2; ++mi)                         \
        _Pragma("unroll") for (int ki = 0; ki < 2; ++ki) {                       \
            av[mi][ki] = *(const short8*)ra[mi][ki];                             \
            gv[mi][ki] = *(const short8*)rg[mi][ki];                             \
            sv[mi][ki] = *(const short8*)rs[mi][ki];                             \
        }                                                                        \
        _Pragma("unroll") for (int ki = 0; ki < 2; ++ki)                         \
        _Pragma("unroll") for (int mi = 0; mi < 2; ++mi)                         \
        _Pragma("unroll") for (int ni = 0; ni < 2; ++ni) {                       \
            accg[mi][ni] = mfma16(av[mi][ki], gv[ni][ki], accg[mi][ni]);         \
            ACC[mi][ni]  = mfma16(av[mi][ki], sv[ni][ki], ACC[mi][ni]);          \
        }                                                                        \
        __syncthreads();                                                         \
    }

    HPHASE(gd0, gd1, accd, 0)
    HPHASE(gx0, gx1, accx, 512)
    HPHASE(gp0, gp1, accp, 1024)
#undef HPHASE

    int colb = bn * 64 + wn * 32 + l15;
    int rowb = bm * 64 + wm * 32 + quad * 4;
#pragma unroll
    for (int ni = 0; ni < 2; ++ni) {
        int col = colb + ni * 16;
        float vbd = bd[col], vbx = bx[col], vbp = bp[col], vbg = bg[col];
#pragma unroll
        for (int mi = 0; mi < 2; ++mi)
#pragma unroll
            for (int r = 0; r < 4; ++r) {
                int row = rowb + mi * 16 + r;
                float gv = 1.f / (1.f + expf(-(accg[mi][ni][r] + vbg)));
                float h = gv * (accd[mi][ni][r] + vbd)
                        + (1.f - gv) * ((accx[mi][ni][r] + vbx) - (accp[mi][ni][r] + vbp));
                H[(size_t)row * 512 + col] = f2bits(h);
            }
    }
}

// ================= generic GEMM: BM=128, BN=64, BK=64 ===========
template<int MODE>
__global__ __launch_bounds__(256) void gemm_t(
    const short* __restrict__ A, int lda,
    const short* __restrict__ BT, int K,
    const float* __restrict__ bias, float* __restrict__ C,
    const float* __restrict__ xsrc, const float* __restrict__ rawm,
    const float* __restrict__ enh, float* __restrict__ outp)
{
    __shared__ __align__(16) short As[8192], Bs[4096];
    int bm = blockIdx.x >> 3, bn = blockIdx.x & 7;
    int t = threadIdx.x, lane = t & 63;
    int wm = (t >> 6) & 1, wn = t >> 7;
    int l15 = lane & 15, quad = lane >> 4;
    int tr8 = t >> 3, pc = t & 7;

    const short* gaA[4]; short* ldA[4];
    const short* gaB[2]; short* ldB[2];
#pragma unroll
    for (int s = 0; s < 4; ++s) {
        int row = s * 32 + tr8;
        int lc = (pc - (row >> 1)) & 7;
        gaA[s] = A + (size_t)(bm * 128 + row) * lda + lc * 8;
        ldA[s] = As + s * 2048 + t * 8;
    }
#pragma unroll
    for (int s = 0; s < 2; ++s) {
        int row = s * 32 + tr8;
        int lc = (pc - (row >> 1)) & 7;
        gaB[s] = BT + (size_t)(bn * 64 + row) * K + lc * 8;
        ldB[s] = Bs + s * 2048 + t * 8;
    }

    const short *ra[4][2], *rb[2][2];
#pragma unroll
    for (int mi = 0; mi < 4; ++mi)
#pragma unroll
        for (int ki = 0; ki < 2; ++ki) {
            int row = wm * 64 + mi * 16 + l15;
            ra[mi][ki] = As + row * 64 + ((ki * 4 + quad + (row >> 1)) & 7) * 8;
        }
#pragma unroll
    for (int ni = 0; ni < 2; ++ni)
#pragma unroll
        for (int ki = 0; ki < 2; ++ki) {
            int row = wn * 32 + ni * 16 + l15;
            rb[ni][ki] = Bs + row * 64 + ((ki * 4 + quad + (row >> 1)) & 7) * 8;
        }

    floatx4 acc[4][2];
#pragma unroll
    for (int mi = 0; mi < 4; ++mi)
#pragma unroll
        for (int ni = 0; ni < 2; ++ni) acc[mi][ni] = (floatx4){0,0,0,0};

    for (int k0 = 0; k0 < K; k0 += 64) {
#pragma unroll
        for (int s = 0; s < 4; ++s) gl2lds16(gaA[s] + k0, ldA[s]);
#pragma unroll
        for (int s = 0; s < 2; ++s) gl2lds16(gaB[s] + k0, ldB[s]);
        __syncthreads();
        short8 av[4][2], bv[2][2];
#pragma unroll
        for (int mi = 0; mi < 4; ++mi)
#pragma unroll
            for (int ki = 0; ki < 2; ++ki) av[mi][ki] = *(const short8*)ra[mi][ki];
#pragma unroll
        for (int ni = 0; ni < 2; ++ni)
#pragma unroll
            for (int ki = 0; ki < 2; ++ki) bv[ni][ki] = *(const short8*)rb[ni][ki];
#pragma unroll
        for (int ki = 0; ki < 2; ++ki)
#pragma unroll
            for (int mi = 0; mi < 4; ++mi)
#pragma unroll
                for (int ni = 0; ni < 2; ++ni)
                    acc[mi][ni] = mfma16(av[mi][ki], bv[ni][ki], acc[mi][ni]);
        __syncthreads();
    }

    int colb = bn * 64 + wn * 32 + l15;
    int rowb = bm * 128 + wm * 64 + quad * 4;
#pragma unroll
    for (int ni = 0; ni < 2; ++ni) {
        int col = colb + ni * 16;
        float bv2 = bias[col];
#pragma unroll
        for (int mi = 0; mi < 4; ++mi)
#pragma unroll
            for (int r = 0; r < 4; ++r) {
                int row = rowb + mi * 16 + r;
                size_t idx = (size_t)row * 512 + col;
                float v = acc[mi][ni][r] + bv2;
                if (MODE == 0) {
                    C[idx] = v;
                } else {
                    float fg = 1.f / (1.f + expf(-v));
                    outp[idx] = xsrc[idx] + rawm[idx] + fg * enh[idx];
                }
            }
    }
}

// ---------------- mid GEMMs with inline S build ----------------
__global__ __launch_bounds__(256) void k_mid2(const float* __restrict__ msum,
                                              const float* __restrict__ pe_proj,
                                              const float* __restrict__ xrm,
                                              const float* __restrict__ dmean,
                                              const float* __restrict__ memW,  const float* __restrict__ memb,
                                              const float* __restrict__ memdW, const float* __restrict__ memdb,
                                              const float* __restrict__ qW,    const float* __restrict__ qb,
                                              const float* __restrict__ curdW, const float* __restrict__ curdb,
                                              float* __restrict__ mg, float* __restrict__ mdrift,
                                              float* __restrict__ qg, float* __restrict__ curd)
{
    __shared__ float sS[4 * 512];
    __shared__ float part[128 * 16];
    int blk = blockIdx.x;
    const float invL = 1.f / 1024.f;
    const float* W; const float* bias; float* out;
    if (blk < 16)      { W = memW;  bias = memb;  out = mg + blk * 2048; }
    else if (blk < 32) { W = memdW; bias = memdb; out = mdrift + (blk - 16) * 2048; }
    else if (blk == 32){ W = qW;    bias = qb;    out = qg; }
    else               { W = curdW; bias = curdb; out = curd; }
    int t = threadIdx.x;
    for (int e = t * 4; e < 2048; e += 1024) {
        int r = e >> 9, d = e & 511;
        float4 o;
        if (blk < 16) {
            int gr = blk * 4 + r; int tt = gr & 15;
            float4 m = *(const float4*)(msum + gr * 512 + d);
            float4 p = *(const float4*)(pe_proj + tt * 512 + d);
            o.x = m.x * invL + p.x; o.y = m.y * invL + p.y;
            o.z = m.z * invL + p.z; o.w = m.w * invL + p.w;
        } else if (blk < 32) {
            int j = (blk - 16) * 4 + r; int tt = j & 15;
            float4 m = *(const float4*)(msum + j * 512 + d);
            float4 p = *(const float4*)(pe_proj + tt * 512 + d);
            o.x = m.x * invL + p.x; o.y = m.y * invL + p.y;
            o.z = m.z * invL + p.z; o.w = m.w * invL + p.w;
            if (tt > 0) {
                float4 m2 = *(const float4*)(msum + (j - 1) * 512 + d);
                float4 p2 = *(const float4*)(pe_proj + (tt - 1) * 512 + d);
                o.x -= m2.x * invL + p2.x; o.y -= m2.y * invL + p2.y;
                o.z -= m2.z * invL + p2.z; o.w -= m2.w * invL + p2.w;
            }
        } else if (blk == 32) {
            float4 m = *(const float4*)(xrm + e);
            o.x = m.x * invL; o.y = m.y * invL; o.z = m.z * invL; o.w = m.w * invL;
        } else {
            float4 m = *(const float4*)(dmean + e);
            o.x = m.x * invL; o.y = m.y * invL; o.z = m.z * invL; o.w = m.w * invL;
        }
        *(float4*)(sS + e) = o;
    }
    __syncthreads();
    int tn = t & 127, dph = t >> 7;
    int n4 = tn * 4;
    float4 acc0 = {0,0,0,0}, acc1 = {0,0,0,0}, acc2 = {0,0,0,0}, acc3 = {0,0,0,0};
    const float* wp = W + (size_t)(dph * 256) * 512 + n4;
    const float* sp = sS + dph * 256;
#pragma unroll 4
    for (int d = 0; d < 256; ++d) {
        float4 w = *(const float4*)(wp + (size_t)d * 512);
        float s0 = sp[d], s1 = sp[512 + d], s2 = sp[1024 + d], s3 = sp[1536 + d];
        acc0.x += s0 * w.x; acc0.y += s0 * w.y; acc0.z += s0 * w.z; acc0.w += s0 * w.w;
        acc1.x += s1 * w.x; acc1.y += s1 * w.y; acc1.z += s1 * w.z; acc1.w += s1 * w.w;
        acc2.x += s2 * w.x; acc2.y += s2 * w.y; acc2.z += s2 * w.z; acc2.w += s2 * w.w;
        acc3.x += s3 * w.x; acc3.y += s3 * w.y; acc3.z += s3 * w.z; acc3.w += s3 * w.w;
    }
    if (dph == 1) {
        *(float4*)(part + tn * 16 + 0)  = acc0;
        *(float4*)(part + tn * 16 + 4)  = acc1;
        *(float4*)(part + tn * 16 + 8)  = acc2;
        *(float4*)(part + tn * 16 + 12) = acc3;
    }
    __syncthreads();
    if (dph == 0) {
        float4 bv = *(const float4*)(bias + n4);
        float4 p0 = *(const float4*)(part + tn * 16 + 0);
        float4 p1 = *(const float4*)(part + tn * 16 + 4);
        float4 p2 = *(const float4*)(part + tn * 16 + 8);
        float4 p3 = *(const float4*)(part + tn * 16 + 12);
        float4 o0, o1, o2, o3;
        o0.x = acc0.x + p0.x + bv.x; o0.y = acc0.y + p0.y + bv.y; o0.z = acc0.z + p0.z + bv.z; o0.w = acc0.w + p0.w + bv.w;
        o1.x = acc1.x + p1.x + bv.x; o1.y = acc1.y + p1.y + bv.y; o1.z = acc1.z + p1.z + bv.z; o1.w = acc1.w + p1.w + bv.w;
        o2.x = acc2.x + p2.x + bv.x; o2.y = acc2.y + p2.y + bv.y; o2.z = acc2.z + p2.z + bv.z; o2.w = acc2.w + p2.w + bv.w;
        o3.x = acc3.x + p3.x + bv.x; o3.y = acc3.y + p3.y + bv.y; o3.z = acc3.z + p3.z + bv.z; o3.w = acc3.w + p3.w + bv.w;
        *(float4*)(out + 0 * 512 + n4) = o0;
        *(float4*)(out + 1 * 512 + n4) = o1;
        *(float4*)(out + 2 * 512 + n4) = o2;
        *(float4*)(out + 3 * 512 + n4) = o3;
    }
}

// ---------------- scores + softmax + pe_att ----------------
__global__ __launch_bounds__(256) void k_attn(const float* __restrict__ qg, const float* __restrict__ mg,
                                              const float* __restrict__ curd, const float* __restrict__ mdrift,
                                              const float* __restrict__ pe_proj,
                                              float* __restrict__ attn, float* __restrict__ pe_att)
{
    int b = blockIdx.x;
    __shared__ float sq[512], sc[512], sscore[16], sattn[16];
    for (int d = threadIdx.x; d < 512; d += 256) { sq[d] = qg[b * 512 + d]; sc[d] = curd[b * 512 + d]; }
    __syncthreads();
    int wv = threadIdx.x >> 6, lane = threadIdx.x & 63;
    for (int t = wv; t < 16; t += 4) {
        float cs = 0.f, dsum = 0.f;
        const float* mgp = mg + (size_t)(b * 16 + t) * 512;
        const float* mdp = mdrift + (size_t)(b * 16 + t) * 512;
        for (int d = lane; d < 512; d += 64) {
            cs += sq[d] * mgp[d];
            float df_ = sc[d] - mdp[d];
            dsum += df_ * df_;
        }
        for (int off = 32; off; off >>= 1) { cs += __shfl_down(cs, off); dsum += __shfl_down(dsum, off); }
        if (lane == 0) sscore[t] = cs * (1.f / 22.627416997969522f) + 0.3f * (-dsum / 512.f);
    }
    __syncthreads();
    if (threadIdx.x == 0) {
        float mx = -1e30f;
        for (int t = 0; t < 16; ++t) mx = fmaxf(mx, sscore[t]);
        float s = 0.f;
        for (int t = 0; t < 16; ++t) { float e = expf(sscore[t] - mx); sattn[t] = e; s += e; }
        for (int t = 0; t < 16; ++t) { sattn[t] /= s; attn[b * 16 + t] = sattn[t]; }
    }
    __syncthreads();
    for (int n = threadIdx.x; n < 512; n += 256) {
        float a = 0.f;
        for (int t = 0; t < 16; ++t) a += sattn[t] * pe_proj[t * 512 + n];
        pe_att[b * 512 + n] = a;
    }
}

// ---------------- enhanced = sum_t attn*ms + pe_att (f32) ; A2 = [x | enh] bf16 ----------------
__global__ __launch_bounds__(128) void k_enh(const float* __restrict__ ms, const float* __restrict__ x,
                                             const float* __restrict__ attn, const float* __restrict__ pe_att,
                                             float* __restrict__ enh, short* __restrict__ A2)
{
    int r = blockIdx.x;
    int b = r >> 10, l = r & 1023;
    __shared__ float sa[16];
    if (threadIdx.x < 16) sa[threadIdx.x] = attn[b * 16 + threadIdx.x];
    __syncthreads();
    int c4 = threadIdx.x << 2;
    float4 pa = *(const float4*)(pe_att + b * 512 + c4);
    float a0 = pa.x, a1 = pa.y, a2 = pa.z, a3 = pa.w;
    const float* base = ms + ((size_t)(b * 16) * 1024 + l) * 512 + c4;
#pragma unroll
    for (int t = 0; t < 16; ++t) {
        float4 v = *(const float4*)(base + (size_t)t * 1024 * 512);
        float w = sa[t];
        a0 += w * v.x; a1 += w * v.y; a2 += w * v.z; a3 += w * v.w;
    }
    size_t oi = (size_t)r * 512 + c4;
    float4 ef; ef.x = a0; ef.y = a1; ef.z = a2; ef.w = a3;
    *(float4*)(enh + oi) = ef;
    float4 xv = *(const float4*)(x + oi);
    short4 xb, eb;
    xb.x = f2bits(xv.x); xb.y = f2bits(xv.y); xb.z = f2bits(xv.z); xb.w = f2bits(xv.w);
    eb.x = f2bits(a0); eb.y = f2bits(a1); eb.z = f2bits(a2); eb.w = f2bits(a3);
    short* arow = A2 + (size_t)r * 1024;
    *(short4*)(arow + c4) = xb;
    *(short4*)(arow + 512 + c4) = eb;
}

extern "C" void kernel_launch(void* const* d_in, const int* in_sizes, int n_in,
                              void* d_out, int out_size, void* d_ws, size_t ws_size,
                              hipStream_t stream)
{
    const float* x       = (const float*)d_in[0];
    const float* ms      = (const float*)d_in[1];
    const float* delta_W = (const float*)d_in[2];  const float* delta_b = (const float*)d_in[3];
    const float* xproj_W = (const float*)d_in[4];  const float* xproj_b = (const float*)d_in[5];
    const float* phys_W  = (const float*)d_in[6];  const float* phys_b  = (const float*)d_in[7];
    const float* gate_W  = (const float*)d_in[8];  const float* gate_b  = (const float*)d_in[9];
    const float* outp_W  = (const float*)d_in[10]; const float* outp_b  = (const float*)d_in[11];
    const float* seq_W   = (const float*)d_in[12]; const float* seq_b   = (const float*)d_in[13];
    const float* q_W     = (const float*)d_in[14]; const float* q_b     = (const float*)d_in[15];
    const float* mem_W   = (const float*)d_in[16]; const float* mem_b   = (const float*)d_in[17];
    const float* curd_W  = (const float*)d_in[18]; const float* curd_b  = (const float*)d_in[19];
    const float* memd_W  = (const float*)d_in[20]; const float* memd_b  = (const float*)d_in[21];
    const float* fuse_W  = (const float*)d_in[22]; const float* fuse_b  = (const float*)d_in[23];
    float* out = (float*)d_out;
    char* wsb = (char*)d_ws;

    short* BT_delta = (short*)(wsb + 0);         // 524288
    short* BT_xproj = (short*)(wsb + 524288);
    short* BT_phys  = (short*)(wsb + 1048576);
    short* BT_outp  = (short*)(wsb + 1572864);
    short* BT_gate  = (short*)(wsb + 2097152);   // 1572864
    short* BT_fuse  = (short*)(wsb + 3670016);   // 1048576
    short* A1       = (short*)(wsb + 4718592);   // 12582912
    short* H        = (short*)(wsb + 17301504);  // 4194304
    float* RAWM     = (float*)(wsb + 21495808);  // 8388608
    float* ENH      = (float*)(wsb + 29884416);  // 8388608
    short* A2       = (short*)(wsb + 38273024);  // 8388608
    float* MSUM     = (float*)(wsb + 46661632);  // 131072
    float* DMEAN    = (float*)(wsb + 46792704);  // 8192
    float* XRM      = (float*)(wsb + 46800896);  // 8192
    float* PEPROJ   = (float*)(wsb + 46809088);  // 32768
    float* MG       = (float*)(wsb + 46841856);  // 131072
    float* MDRIFT   = (float*)(wsb + 46972928);  // 131072
    float* QG       = (float*)(wsb + 47104000);  // 8192
    float* CURD     = (float*)(wsb + 47112192);  // 8192
    float* ATTN     = (float*)(wsb + 47120384);  // 1024
    float* PEATT    = (float*)(wsb + 47121408);  // 8192

    // zero atomic accumulators (MSUM|DMEAN|XRM contiguous)
    hipMemsetAsync(wsb + 46661632, 0, 131072 + 8192 + 8192, stream);

    k_front<<<5520, 256, 0, stream>>>(delta_W, xproj_W, phys_W, outp_W, gate_W, fuse_W,
                                      BT_delta, BT_xproj, BT_phys, BT_outp, BT_gate, BT_fuse,
                                      x, ms, seq_W, seq_b, A1, PEPROJ, MSUM, DMEAN);

    gemm_h_t<<<512, 256, 0, stream>>>(A1, BT_delta, BT_xproj, BT_phys, BT_gate,
                                      delta_b, xproj_b, phys_b, gate_b, H);
    gemm_t<0><<<256, 256, 0, stream>>>(H, 512, BT_outp, 512, outp_b, RAWM,
                                       nullptr, nullptr, nullptr, nullptr);
    k_rmean<<<128, 256, 0, stream>>>(x, RAWM, XRM);

    k_mid2<<<34, 256, 0, stream>>>(MSUM, PEPROJ, XRM, DMEAN,
                                   mem_W, mem_b, memd_W, memd_b,
                                   q_W, q_b, curd_W, curd_b,
                                   MG, MDRIFT, QG, CURD);
    k_attn<<<4, 256, 0, stream>>>(QG, MG, CURD, MDRIFT, PEPROJ, ATTN, PEATT);
    k_enh<<<4096, 128, 0, stream>>>(ms, x, ATTN, PEATT, ENH, A2);

    gemm_t<2><<<256, 256, 0, stream>>>(A2, 1024, BT_fuse, 1024, fuse_b, nullptr,
                                       x, RAWM, ENH, out);
}

// Round 7
// 403.353 us; speedup vs baseline: 1.2126x; 1.2126x over previous
//
#include <hip/hip_runtime.h>
#include <hip/hip_bf16.h>
#include <math.h>

typedef __attribute__((ext_vector_type(8))) short short8;
typedef __attribute__((ext_vector_type(4))) float floatx4;

__device__ __forceinline__ short f2bits(float f) {
    union { float f; unsigned u; } cv; cv.f = f;
    unsigned u = cv.u;
    u += 0x7fffu + ((u >> 16) & 1u);   // RNE fp32 -> bf16
    return (short)(u >> 16);
}

__device__ __forceinline__ floatx4 mfma16(short8 a, short8 b, floatx4 c) {
    return __builtin_amdgcn_mfma_f32_16x16x32_bf16(a, b, c, 0, 0, 0);
}

typedef const __attribute__((address_space(1))) unsigned int* gas_ptr;
typedef __attribute__((address_space(3))) unsigned int* las_ptr;

// async 16B global->LDS: lands at (wave-uniform base + lane*16)
__device__ __forceinline__ void gl2lds16(const short* g, short* l) {
    __builtin_amdgcn_global_load_lds((gas_ptr)g, (las_ptr)l, 16, 0, 0);
}

// ================= k_front: fused tr / pe / prep / msum / dmean(+xsum) =================
// blocks [0,2304): weight transpose   [2304,2320): pe_proj
// [2320,4368): A1 build               [4368,4880): msum   [4880,4912): dmean+xsum
__global__ __launch_bounds__(256) void k_front(
    const float* __restrict__ w_delta, const float* __restrict__ w_xproj,
    const float* __restrict__ w_phys,  const float* __restrict__ w_outp,
    const float* __restrict__ w_gate,  const float* __restrict__ w_fuse,
    short* __restrict__ bt_delta, short* __restrict__ bt_xproj,
    short* __restrict__ bt_phys,  short* __restrict__ bt_outp,
    short* __restrict__ bt_gate,  short* __restrict__ bt_fuse,
    const float* __restrict__ x, const float* __restrict__ ms,
    const float* __restrict__ seqW, const float* __restrict__ seqb,
    short* __restrict__ A1, float* __restrict__ pe_proj,
    float* __restrict__ msum, float* __restrict__ dmean,
    float* __restrict__ xrm)
{
    __shared__ float sf[32 * 33];
    __shared__ float pe[512];
    int bi = blockIdx.x;
    int t = threadIdx.x;
    if (bi < 2304) {
        // ---- 32x32 LDS transpose + fp32->bf16 ----
        int id = bi;
        const float* W; short* BT; int K; int local;
        if (id < 256)        { W = w_delta; BT = bt_delta; K = 512;  local = id; }
        else if (id < 512)   { W = w_xproj; BT = bt_xproj; K = 512;  local = id - 256; }
        else if (id < 768)   { W = w_phys;  BT = bt_phys;  K = 512;  local = id - 512; }
        else if (id < 1024)  { W = w_outp;  BT = bt_outp;  K = 512;  local = id - 768; }
        else if (id < 1792)  { W = w_gate;  BT = bt_gate;  K = 1536; local = id - 1024; }
        else                 { W = w_fuse;  BT = bt_fuse;  K = 1024; local = id - 1792; }
        int kt = local >> 4, nt = local & 15;
        int r = t >> 3, c = (t & 7) * 4;
        float4 v = *(const float4*)(W + (size_t)(kt * 32 + r) * 512 + nt * 32 + c);
        sf[r * 33 + c + 0] = v.x; sf[r * 33 + c + 1] = v.y;
        sf[r * 33 + c + 2] = v.z; sf[r * 33 + c + 3] = v.w;
        __syncthreads();
        int n = t >> 3, k4 = (t & 7) * 4;
        short4 o;
        o.x = f2bits(sf[(k4 + 0) * 33 + n]);
        o.y = f2bits(sf[(k4 + 1) * 33 + n]);
        o.z = f2bits(sf[(k4 + 2) * 33 + n]);
        o.w = f2bits(sf[(k4 + 3) * 33 + n]);
        *(short4*)(BT + (size_t)(nt * 32 + n) * K + kt * 32 + k4) = o;
    } else if (bi < 2320) {
        // ---- pe_proj[t][n] ----
        int tt = bi - 2304;
        for (int d = t; d < 512; d += 256) {
            int i = d >> 1;
            float div = expf(-9.210340371976184f * (2.f * i / 512.f));
            float ang = (float)(tt + 1) * div;
            pe[d] = (d & 1) ? cosf(ang) : sinf(ang);
        }
        __syncthreads();
        for (int n = t; n < 512; n += 256) {
            float acc = 0.f;
            for (int d = 0; d < 512; ++d) acc += pe[d] * seqW[(size_t)d * 512 + n];
            pe_proj[tt * 512 + n] = acc + seqb[n];
        }
    } else if (bi < 4368) {
        // ---- A1 = [delta | x | x_phys] bf16 ----
        int gid = (bi - 2320) * 256 + t;
        int r = gid >> 7;
        int c4 = (gid & 127) << 2;
        int b = r >> 10, l = r & 1023;
        float4 xv = *(const float4*)(x + (size_t)r * 512 + c4);
        float4 pv = *(const float4*)(ms + ((size_t)(b * 16 + 15) * 1024 + l) * 512 + c4);
        short4 xb, pb, db;
        xb.x = f2bits(xv.x); xb.y = f2bits(xv.y); xb.z = f2bits(xv.z); xb.w = f2bits(xv.w);
        pb.x = f2bits(pv.x); pb.y = f2bits(pv.y); pb.z = f2bits(pv.z); pb.w = f2bits(pv.w);
        db.x = f2bits(xv.x - pv.x); db.y = f2bits(xv.y - pv.y);
        db.z = f2bits(xv.z - pv.z); db.w = f2bits(xv.w - pv.w);
        short* row = A1 + (size_t)r * 1536;
        *(short4*)(row + c4) = db;
        *(short4*)(row + 512 + c4) = xb;
        *(short4*)(row + 1024 + c4) = pb;
    } else if (bi < 4880) {
        // ---- msum: dual independent accumulator streams ----
        int blk = bi - 4368;
        int bt = blk >> 3, chunk = blk & 7;
        int half = t >> 7, c4 = (t & 127) << 2;
        const float* base = ms + ((size_t)(bt * 1024 + chunk * 128 + half * 64)) * 512 + c4;
        const float* base2 = base + (size_t)32 * 512;
        float a0 = 0, a1 = 0, a2 = 0, a3 = 0;
        float b0 = 0, b1 = 0, b2 = 0, b3 = 0;
        for (int l = 0; l < 32; ++l) {
            float4 v = *(const float4*)(base + (size_t)l * 512);
            float4 w = *(const float4*)(base2 + (size_t)l * 512);
            a0 += v.x; a1 += v.y; a2 += v.z; a3 += v.w;
            b0 += w.x; b1 += w.y; b2 += w.z; b3 += w.w;
        }
        float* dst = msum + bt * 512 + c4;
        atomicAdd(dst + 0, a0 + b0); atomicAdd(dst + 1, a1 + b1);
        atomicAdd(dst + 2, a2 + b2); atomicAdd(dst + 3, a3 + b3);
    } else {
        // ---- dmean + xsum (xsum feeds xrm; rawm part added by gemm_t<0>) ----
        int blk = bi - 4880;
        int b = blk >> 3, chunk = blk & 7;
        int half = t >> 7, c4 = (t & 127) << 2;
        float a0 = 0, a1 = 0, a2 = 0, a3 = 0;
        float x0 = 0, x1 = 0, x2 = 0, x3 = 0;
        for (int l = 0; l < 64; ++l) {
            int lr = chunk * 128 + half * 64 + l;
            int r = b * 1024 + lr;
            float4 xv = *(const float4*)(x + (size_t)r * 512 + c4);
            float4 pv = *(const float4*)(ms + ((size_t)(b * 16 + 15) * 1024 + lr) * 512 + c4);
            a0 += xv.x - pv.x; a1 += xv.y - pv.y; a2 += xv.z - pv.z; a3 += xv.w - pv.w;
            x0 += xv.x; x1 += xv.y; x2 += xv.z; x3 += xv.w;
        }
        float* dst = dmean + b * 512 + c4;
        atomicAdd(dst + 0, a0); atomicAdd(dst + 1, a1);
        atomicAdd(dst + 2, a2); atomicAdd(dst + 3, a3);
        float* dx = xrm + b * 512 + c4;
        atomicAdd(dx + 0, x0); atomicAdd(dx + 1, x1);
        atomicAdd(dx + 2, x2); atomicAdd(dx + 3, x3);
    }
}

// ================= fused front GEMM -> H (bf16).  BM=BN=64, BK=64 =================
__global__ __launch_bounds__(256) void gemm_h_t(
    const short* __restrict__ A1,
    const short* __restrict__ BTd, const short* __restrict__ BTx,
    const short* __restrict__ BTp, const short* __restrict__ BTg,
    const float* __restrict__ bd, const float* __restrict__ bx,
    const float* __restrict__ bp, const float* __restrict__ bg,
    short* __restrict__ H)
{
    __shared__ __align__(16) short As[4096], Bgs[4096], Bss[4096];
    int bm = blockIdx.x >> 3, bn = blockIdx.x & 7;
    int t = threadIdx.x, lane = t & 63;
    int wm = (t >> 6) & 1, wn = t >> 7;
    int l15 = lane & 15, quad = lane >> 4;
    int tr8 = t >> 3, pc = t & 7;

    int row0 = tr8, row1 = 32 + tr8;
    int lc0 = (pc - (row0 >> 1)) & 7, lc1 = (pc - (row1 >> 1)) & 7;
    const short* gaA0 = A1 + (size_t)(bm * 64 + row0) * 1536 + lc0 * 8;
    const short* gaA1 = A1 + (size_t)(bm * 64 + row1) * 1536 + lc1 * 8;
    const short* gaG0 = BTg + (size_t)(bn * 64 + row0) * 1536 + lc0 * 8;
    const short* gaG1 = BTg + (size_t)(bn * 64 + row1) * 1536 + lc1 * 8;
    const short* gd0 = BTd + (size_t)(bn * 64 + row0) * 512 + lc0 * 8;
    const short* gd1 = BTd + (size_t)(bn * 64 + row1) * 512 + lc1 * 8;
    const short* gx0 = BTx + (size_t)(bn * 64 + row0) * 512 + lc0 * 8;
    const short* gx1 = BTx + (size_t)(bn * 64 + row1) * 512 + lc1 * 8;
    const short* gp0 = BTp + (size_t)(bn * 64 + row0) * 512 + lc0 * 8;
    const short* gp1 = BTp + (size_t)(bn * 64 + row1) * 512 + lc1 * 8;
    short* ldA0 = As + t * 8;  short* ldA1 = As + 2048 + t * 8;
    short* ldG0 = Bgs + t * 8; short* ldG1 = Bgs + 2048 + t * 8;
    short* ldS0 = Bss + t * 8; short* ldS1 = Bss + 2048 + t * 8;

    const short *ra[2][2], *rg[2][2], *rs[2][2];
#pragma unroll
    for (int mi = 0; mi < 2; ++mi)
#pragma unroll
        for (int ki = 0; ki < 2; ++ki) {
            int row = wm * 32 + mi * 16 + l15;
            int off = row * 64 + ((ki * 4 + quad + (row >> 1)) & 7) * 8;
            ra[mi][ki] = As + off;
            int rowb = wn * 32 + mi * 16 + l15;
            int offb = rowb * 64 + ((ki * 4 + quad + (rowb >> 1)) & 7) * 8;
            rg[mi][ki] = Bgs + offb;
            rs[mi][ki] = Bss + offb;
        }

    floatx4 accg[2][2], accd[2][2], accx[2][2], accp[2][2];
#pragma unroll
    for (int i = 0; i < 2; ++i)
#pragma unroll
        for (int j = 0; j < 2; ++j) {
            accg[i][j] = (floatx4){0,0,0,0}; accd[i][j] = (floatx4){0,0,0,0};
            accx[i][j] = (floatx4){0,0,0,0}; accp[i][j] = (floatx4){0,0,0,0};
        }

#define HPHASE(S0, S1, ACC, KB)                                                  \
    for (int k0 = 0; k0 < 512; k0 += 64) {                                       \
        gl2lds16(gaA0 + KB + k0, ldA0); gl2lds16(gaA1 + KB + k0, ldA1);          \
        gl2lds16(gaG0 + KB + k0, ldG0); gl2lds16(gaG1 + KB + k0, ldG1);          \
        gl2lds16(S0 + k0, ldS0);        gl2lds16(S1 + k0, ldS1);                 \
        __syncthreads();                                                         \
        short8 av[2][2], gv[2][2], sv[2][2];                                     \
        _Pragma("unroll") for (int mi = 0; mi < 2; ++mi)                         \
        _Pragma("unroll") for (int ki = 0; ki < 2; ++ki) {                       \
            av[mi][ki] = *(const short8*)ra[mi][ki];                             \
            gv[mi][ki] = *(const short8*)rg[mi][ki];                             \
            sv[mi][ki] = *(const short8*)rs[mi][ki];                             \
        }                                                                        \
        _Pragma("unroll") for (int ki = 0; ki < 2; ++ki)                         \
        _Pragma("unroll") for (int mi = 0; mi < 2; ++mi)                         \
        _Pragma("unroll") for (int ni = 0; ni < 2; ++ni) {                       \
            accg[mi][ni] = mfma16(av[mi][ki], gv[ni][ki], accg[mi][ni]);         \
            ACC[mi][ni]  = mfma16(av[mi][ki], sv[ni][ki], ACC[mi][ni]);          \
        }                                                                        \
        __syncthreads();                                                         \
    }

    HPHASE(gd0, gd1, accd, 0)
    HPHASE(gx0, gx1, accx, 512)
    HPHASE(gp0, gp1, accp, 1024)
#undef HPHASE

    int colb = bn * 64 + wn * 32 + l15;
    int rowb = bm * 64 + wm * 32 + quad * 4;
#pragma unroll
    for (int ni = 0; ni < 2; ++ni) {
        int col = colb + ni * 16;
        float vbd = bd[col], vbx = bx[col], vbp = bp[col], vbg = bg[col];
#pragma unroll
        for (int mi = 0; mi < 2; ++mi)
#pragma unroll
            for (int r = 0; r < 4; ++r) {
                int row = rowb + mi * 16 + r;
                float gv = 1.f / (1.f + expf(-(accg[mi][ni][r] + vbg)));
                float h = gv * (accd[mi][ni][r] + vbd)
                        + (1.f - gv) * ((accx[mi][ni][r] + vbx) - (accp[mi][ni][r] + vbp));
                H[(size_t)row * 512 + col] = f2bits(h);
            }
    }
}

// ================= generic GEMM: BM=128, BN=64, BK=64 ===========
// MODE 0: C = acc + bias; also atomically accumulates per-column rawm sums into xrm.
// MODE 2: out = x + rawm + sigmoid(acc+bias)*enh.
template<int MODE>
__global__ __launch_bounds__(256) void gemm_t(
    const short* __restrict__ A, int lda,
    const short* __restrict__ BT, int K,
    const float* __restrict__ bias, float* __restrict__ C,
    const float* __restrict__ xsrc, const float* __restrict__ rawm,
    const float* __restrict__ enh, float* __restrict__ outp,
    float* __restrict__ xrm)
{
    __shared__ __align__(16) short As[8192], Bs[4096];
    int bm = blockIdx.x >> 3, bn = blockIdx.x & 7;
    int t = threadIdx.x, lane = t & 63;
    int wm = (t >> 6) & 1, wn = t >> 7;
    int l15 = lane & 15, quad = lane >> 4;
    int tr8 = t >> 3, pc = t & 7;

    const short* gaA[4]; short* ldA[4];
    const short* gaB[2]; short* ldB[2];
#pragma unroll
    for (int s = 0; s < 4; ++s) {
        int row = s * 32 + tr8;
        int lc = (pc - (row >> 1)) & 7;
        gaA[s] = A + (size_t)(bm * 128 + row) * lda + lc * 8;
        ldA[s] = As + s * 2048 + t * 8;
    }
#pragma unroll
    for (int s = 0; s < 2; ++s) {
        int row = s * 32 + tr8;
        int lc = (pc - (row >> 1)) & 7;
        gaB[s] = BT + (size_t)(bn * 64 + row) * K + lc * 8;
        ldB[s] = Bs + s * 2048 + t * 8;
    }

    const short *ra[4][2], *rb[2][2];
#pragma unroll
    for (int mi = 0; mi < 4; ++mi)
#pragma unroll
        for (int ki = 0; ki < 2; ++ki) {
            int row = wm * 64 + mi * 16 + l15;
            ra[mi][ki] = As + row * 64 + ((ki * 4 + quad + (row >> 1)) & 7) * 8;
        }
#pragma unroll
    for (int ni = 0; ni < 2; ++ni)
#pragma unroll
        for (int ki = 0; ki < 2; ++ki) {
            int row = wn * 32 + ni * 16 + l15;
            rb[ni][ki] = Bs + row * 64 + ((ki * 4 + quad + (row >> 1)) & 7) * 8;
        }

    floatx4 acc[4][2];
#pragma unroll
    for (int mi = 0; mi < 4; ++mi)
#pragma unroll
        for (int ni = 0; ni < 2; ++ni) acc[mi][ni] = (floatx4){0,0,0,0};

    for (int k0 = 0; k0 < K; k0 += 64) {
#pragma unroll
        for (int s = 0; s < 4; ++s) gl2lds16(gaA[s] + k0, ldA[s]);
#pragma unroll
        for (int s = 0; s < 2; ++s) gl2lds16(gaB[s] + k0, ldB[s]);
        __syncthreads();
        short8 av[4][2], bv[2][2];
#pragma unroll
        for (int mi = 0; mi < 4; ++mi)
#pragma unroll
            for (int ki = 0; ki < 2; ++ki) av[mi][ki] = *(const short8*)ra[mi][ki];
#pragma unroll
        for (int ni = 0; ni < 2; ++ni)
#pragma unroll
            for (int ki = 0; ki < 2; ++ki) bv[ni][ki] = *(const short8*)rb[ni][ki];
#pragma unroll
        for (int ki = 0; ki < 2; ++ki)
#pragma unroll
            for (int mi = 0; mi < 4; ++mi)
#pragma unroll
                for (int ni = 0; ni < 2; ++ni)
                    acc[mi][ni] = mfma16(av[mi][ki], bv[ni][ki], acc[mi][ni]);
        __syncthreads();
    }

    int colb = bn * 64 + wn * 32 + l15;
    int rowb = bm * 128 + wm * 64 + quad * 4;
#pragma unroll
    for (int ni = 0; ni < 2; ++ni) {
        int col = colb + ni * 16;
        float bv2 = bias[col];
        float csum = 0.f;
#pragma unroll
        for (int mi = 0; mi < 4; ++mi)
#pragma unroll
            for (int r = 0; r < 4; ++r) {
                int row = rowb + mi * 16 + r;
                size_t idx = (size_t)row * 512 + col;
                float v = acc[mi][ni][r] + bv2;
                if (MODE == 0) {
                    C[idx] = v;
                    csum += v;
                } else {
                    float fg = 1.f / (1.f + expf(-v));
                    outp[idx] = xsrc[idx] + rawm[idx] + fg * enh[idx];
                }
            }
        if (MODE == 0) {
            // rawm contribution to xrm[b][col]; b = bm>>3 (BM=128 stays in one b)
            atomicAdd(xrm + (bm >> 3) * 512 + col, csum);
        }
    }
}

// ---------------- mid GEMMs with inline S build ----------------
__global__ __launch_bounds__(256) void k_mid2(const float* __restrict__ msum,
                                              const float* __restrict__ pe_proj,
                                              const float* __restrict__ xrm,
                                              const float* __restrict__ dmean,
                                              const float* __restrict__ memW,  const float* __restrict__ memb,
                                              const float* __restrict__ memdW, const float* __restrict__ memdb,
                                              const float* __restrict__ qW,    const float* __restrict__ qb,
                                              const float* __restrict__ curdW, const float* __restrict__ curdb,
                                              float* __restrict__ mg, float* __restrict__ mdrift,
                                              float* __restrict__ qg, float* __restrict__ curd)
{
    __shared__ float sS[4 * 512];
    __shared__ float part[128 * 16];
    int blk = blockIdx.x;
    const float invL = 1.f / 1024.f;
    const float* W; const float* bias; float* out;
    if (blk < 16)      { W = memW;  bias = memb;  out = mg + blk * 2048; }
    else if (blk < 32) { W = memdW; bias = memdb; out = mdrift + (blk - 16) * 2048; }
    else if (blk == 32){ W = qW;    bias = qb;    out = qg; }
    else               { W = curdW; bias = curdb; out = curd; }
    int t = threadIdx.x;
    for (int e = t * 4; e < 2048; e += 1024) {
        int r = e >> 9, d = e & 511;
        float4 o;
        if (blk < 16) {
            int gr = blk * 4 + r; int tt = gr & 15;
            float4 m = *(const float4*)(msum + gr * 512 + d);
            float4 p = *(const float4*)(pe_proj + tt * 512 + d);
            o.x = m.x * invL + p.x; o.y = m.y * invL + p.y;
            o.z = m.z * invL + p.z; o.w = m.w * invL + p.w;
        } else if (blk < 32) {
            int j = (blk - 16) * 4 + r; int tt = j & 15;
            float4 m = *(const float4*)(msum + j * 512 + d);
            float4 p = *(const float4*)(pe_proj + tt * 512 + d);
            o.x = m.x * invL + p.x; o.y = m.y * invL + p.y;
            o.z = m.z * invL + p.z; o.w = m.w * invL + p.w;
            if (tt > 0) {
                float4 m2 = *(const float4*)(msum + (j - 1) * 512 + d);
                float4 p2 = *(const float4*)(pe_proj + (tt - 1) * 512 + d);
                o.x -= m2.x * invL + p2.x; o.y -= m2.y * invL + p2.y;
                o.z -= m2.z * invL + p2.z; o.w -= m2.w * invL + p2.w;
            }
        } else if (blk == 32) {
            float4 m = *(const float4*)(xrm + e);
            o.x = m.x * invL; o.y = m.y * invL; o.z = m.z * invL; o.w = m.w * invL;
        } else {
            float4 m = *(const float4*)(dmean + e);
            o.x = m.x * invL; o.y = m.y * invL; o.z = m.z * invL; o.w = m.w * invL;
        }
        *(float4*)(sS + e) = o;
    }
    __syncthreads();
    int tn = t & 127, dph = t >> 7;
    int n4 = tn * 4;
    float4 acc0 = {0,0,0,0}, acc1 = {0,0,0,0}, acc2 = {0,0,0,0}, acc3 = {0,0,0,0};
    const float* wp = W + (size_t)(dph * 256) * 512 + n4;
    const float* sp = sS + dph * 256;
#pragma unroll 4
    for (int d = 0; d < 256; ++d) {
        float4 w = *(const float4*)(wp + (size_t)d * 512);
        float s0 = sp[d], s1 = sp[512 + d], s2 = sp[1024 + d], s3 = sp[1536 + d];
        acc0.x += s0 * w.x; acc0.y += s0 * w.y; acc0.z += s0 * w.z; acc0.w += s0 * w.w;
        acc1.x += s1 * w.x; acc1.y += s1 * w.y; acc1.z += s1 * w.z; acc1.w += s1 * w.w;
        acc2.x += s2 * w.x; acc2.y += s2 * w.y; acc2.z += s2 * w.z; acc2.w += s2 * w.w;
        acc3.x += s3 * w.x; acc3.y += s3 * w.y; acc3.z += s3 * w.z; acc3.w += s3 * w.w;
    }
    if (dph == 1) {
        *(float4*)(part + tn * 16 + 0)  = acc0;
        *(float4*)(part + tn * 16 + 4)  = acc1;
        *(float4*)(part + tn * 16 + 8)  = acc2;
        *(float4*)(part + tn * 16 + 12) = acc3;
    }
    __syncthreads();
    if (dph == 0) {
        float4 bv = *(const float4*)(bias + n4);
        float4 p0 = *(const float4*)(part + tn * 16 + 0);
        float4 p1 = *(const float4*)(part + tn * 16 + 4);
        float4 p2 = *(const float4*)(part + tn * 16 + 8);
        float4 p3 = *(const float4*)(part + tn * 16 + 12);
        float4 o0, o1, o2, o3;
        o0.x = acc0.x + p0.x + bv.x; o0.y = acc0.y + p0.y + bv.y; o0.z = acc0.z + p0.z + bv.z; o0.w = acc0.w + p0.w + bv.w;
        o1.x = acc1.x + p1.x + bv.x; o1.y = acc1.y + p1.y + bv.y; o1.z = acc1.z + p1.z + bv.z; o1.w = acc1.w + p1.w + bv.w;
        o2.x = acc2.x + p2.x + bv.x; o2.y = acc2.y + p2.y + bv.y; o2.z = acc2.z + p2.z + bv.z; o2.w = acc2.w + p2.w + bv.w;
        o3.x = acc3.x + p3.x + bv.x; o3.y = acc3.y + p3.y + bv.y; o3.z = acc3.z + p3.z + bv.z; o3.w = acc3.w + p3.w + bv.w;
        *(float4*)(out + 0 * 512 + n4) = o0;
        *(float4*)(out + 1 * 512 + n4) = o1;
        *(float4*)(out + 2 * 512 + n4) = o2;
        *(float4*)(out + 3 * 512 + n4) = o3;
    }
}

// ---------------- scores + softmax + pe_att ----------------
__global__ __launch_bounds__(256) void k_attn(const float* __restrict__ qg, const float* __restrict__ mg,
                                              const float* __restrict__ curd, const float* __restrict__ mdrift,
                                              const float* __restrict__ pe_proj,
                                              float* __restrict__ attn, float* __restrict__ pe_att)
{
    int b = blockIdx.x;
    __shared__ float sq[512], sc[512], sscore[16], sattn[16];
    for (int d = threadIdx.x; d < 512; d += 256) { sq[d] = qg[b * 512 + d]; sc[d] = curd[b * 512 + d]; }
    __syncthreads();
    int wv = threadIdx.x >> 6, lane = threadIdx.x & 63;
    for (int t = wv; t < 16; t += 4) {
        float cs = 0.f, dsum = 0.f;
        const float* mgp = mg + (size_t)(b * 16 + t) * 512;
        const float* mdp = mdrift + (size_t)(b * 16 + t) * 512;
        for (int d = lane; d < 512; d += 64) {
            cs += sq[d] * mgp[d];
            float df_ = sc[d] - mdp[d];
            dsum += df_ * df_;
        }
        for (int off = 32; off; off >>= 1) { cs += __shfl_down(cs, off); dsum += __shfl_down(dsum, off); }
        if (lane == 0) sscore[t] = cs * (1.f / 22.627416997969522f) + 0.3f * (-dsum / 512.f);
    }
    __syncthreads();
    if (threadIdx.x == 0) {
        float mx = -1e30f;
        for (int t = 0; t < 16; ++t) mx = fmaxf(mx, sscore[t]);
        float s = 0.f;
        for (int t = 0; t < 16; ++t) { float e = expf(sscore[t] - mx); sattn[t] = e; s += e; }
        for (int t = 0; t < 16; ++t) { sattn[t] /= s; attn[b * 16 + t] = sattn[t]; }
    }
    __syncthreads();
    for (int n = threadIdx.x; n < 512; n += 256) {
        float a = 0.f;
        for (int t = 0; t < 16; ++t) a += sattn[t] * pe_proj[t * 512 + n];
        pe_att[b * 512 + n] = a;
    }
}

// ---------------- enhanced = sum_t attn*ms + pe_att (f32) ; A2 = [x | enh] bf16 ----------------
__global__ __launch_bounds__(128) void k_enh(const float* __restrict__ ms, const float* __restrict__ x,
                                             const float* __restrict__ attn, const float* __restrict__ pe_att,
                                             float* __restrict__ enh, short* __restrict__ A2)
{
    int r = blockIdx.x;
    int b = r >> 10, l = r & 1023;
    __shared__ float sa[16];
    if (threadIdx.x < 16) sa[threadIdx.x] = attn[b * 16 + threadIdx.x];
    __syncthreads();
    int c4 = threadIdx.x << 2;
    float4 pa = *(const float4*)(pe_att + b * 512 + c4);
    float a0 = pa.x, a1 = pa.y, a2 = pa.z, a3 = pa.w;
    const float* base = ms + ((size_t)(b * 16) * 1024 + l) * 512 + c4;
#pragma unroll
    for (int t = 0; t < 16; ++t) {
        float4 v = *(const float4*)(base + (size_t)t * 1024 * 512);
        float w = sa[t];
        a0 += w * v.x; a1 += w * v.y; a2 += w * v.z; a3 += w * v.w;
    }
    size_t oi = (size_t)r * 512 + c4;
    float4 ef; ef.x = a0; ef.y = a1; ef.z = a2; ef.w = a3;
    *(float4*)(enh + oi) = ef;
    float4 xv = *(const float4*)(x + oi);
    short4 xb, eb;
    xb.x = f2bits(xv.x); xb.y = f2bits(xv.y); xb.z = f2bits(xv.z); xb.w = f2bits(xv.w);
    eb.x = f2bits(a0); eb.y = f2bits(a1); eb.z = f2bits(a2); eb.w = f2bits(a3);
    short* arow = A2 + (size_t)r * 1024;
    *(short4*)(arow + c4) = xb;
    *(short4*)(arow + 512 + c4) = eb;
}

extern "C" void kernel_launch(void* const* d_in, const int* in_sizes, int n_in,
                              void* d_out, int out_size, void* d_ws, size_t ws_size,
                              hipStream_t stream)
{
    const float* x       = (const float*)d_in[0];
    const float* ms      = (const float*)d_in[1];
    const float* delta_W = (const float*)d_in[2];  const float* delta_b = (const float*)d_in[3];
    const float* xproj_W = (const float*)d_in[4];  const float* xproj_b = (const float*)d_in[5];
    const float* phys_W  = (const float*)d_in[6];  const float* phys_b  = (const float*)d_in[7];
    const float* gate_W  = (const float*)d_in[8];  const float* gate_b  = (const float*)d_in[9];
    const float* outp_W  = (const float*)d_in[10]; const float* outp_b  = (const float*)d_in[11];
    const float* seq_W   = (const float*)d_in[12]; const float* seq_b   = (const float*)d_in[13];
    const float* q_W     = (const float*)d_in[14]; const float* q_b     = (const float*)d_in[15];
    const float* mem_W   = (const float*)d_in[16]; const float* mem_b   = (const float*)d_in[17];
    const float* curd_W  = (const float*)d_in[18]; const float* curd_b  = (const float*)d_in[19];
    const float* memd_W  = (const float*)d_in[20]; const float* memd_b  = (const float*)d_in[21];
    const float* fuse_W  = (const float*)d_in[22]; const float* fuse_b  = (const float*)d_in[23];
    float* out = (float*)d_out;
    char* wsb = (char*)d_ws;

    short* BT_delta = (short*)(wsb + 0);         // 524288
    short* BT_xproj = (short*)(wsb + 524288);
    short* BT_phys  = (short*)(wsb + 1048576);
    short* BT_outp  = (short*)(wsb + 1572864);
    short* BT_gate  = (short*)(wsb + 2097152);   // 1572864
    short* BT_fuse  = (short*)(wsb + 3670016);   // 1048576
    short* A1       = (short*)(wsb + 4718592);   // 12582912
    short* H        = (short*)(wsb + 17301504);  // 4194304
    float* RAWM     = (float*)(wsb + 21495808);  // 8388608
    float* ENH      = (float*)(wsb + 29884416);  // 8388608
    short* A2       = (short*)(wsb + 38273024);  // 8388608
    float* MSUM     = (float*)(wsb + 46661632);  // 131072
    float* DMEAN    = (float*)(wsb + 46792704);  // 8192
    float* XRM      = (float*)(wsb + 46800896);  // 8192
    float* PEPROJ   = (float*)(wsb + 46809088);  // 32768
    float* MG       = (float*)(wsb + 46841856);  // 131072
    float* MDRIFT   = (float*)(wsb + 46972928);  // 131072
    float* QG       = (float*)(wsb + 47104000);  // 8192
    float* CURD     = (float*)(wsb + 47112192);  // 8192
    float* ATTN     = (float*)(wsb + 47120384);  // 1024
    float* PEATT    = (float*)(wsb + 47121408);  // 8192

    // zero atomic accumulators (MSUM|DMEAN|XRM contiguous)
    hipMemsetAsync(wsb + 46661632, 0, 131072 + 8192 + 8192, stream);

    k_front<<<4912, 256, 0, stream>>>(delta_W, xproj_W, phys_W, outp_W, gate_W, fuse_W,
                                      BT_delta, BT_xproj, BT_phys, BT_outp, BT_gate, BT_fuse,
                                      x, ms, seq_W, seq_b, A1, PEPROJ, MSUM, DMEAN, XRM);

    gemm_h_t<<<512, 256, 0, stream>>>(A1, BT_delta, BT_xproj, BT_phys, BT_gate,
                                      delta_b, xproj_b, phys_b, gate_b, H);
    gemm_t<0><<<256, 256, 0, stream>>>(H, 512, BT_outp, 512, outp_b, RAWM,
                                       nullptr, nullptr, nullptr, nullptr, XRM);

    k_mid2<<<34, 256, 0, stream>>>(MSUM, PEPROJ, XRM, DMEAN,
                                   mem_W, mem_b, memd_W, memd_b,
                                   q_W, q_b, curd_W, curd_b,
                                   MG, MDRIFT, QG, CURD);
    k_attn<<<4, 256, 0, stream>>>(QG, MG, CURD, MDRIFT, PEPROJ, ATTN, PEATT);
    k_enh<<<4096, 128, 0, stream>>>(ms, x, ATTN, PEATT, ENH, A2);

    gemm_t<2><<<256, 256, 0, stream>>>(A2, 1024, BT_fuse, 1024, fuse_b, nullptr,
                                       x, RAWM, ENH, out, nullptr);
}